// Round 4
// baseline (419.714 us; speedup 1.0000x reference)
//
#include <hip/hip_runtime.h>
#include <float.h>
#include <stdint.h>

constexpr int D_MODEL = 1024;
constexpr int DICT    = 16384;
constexpr int TOPK    = 8;
constexpr int NCAND   = 16;
constexpr int NTOK    = 4096;      // B*T
constexpr long long COEFF_COUNT = (long long)NTOK * DICT;

typedef __attribute__((ext_vector_type(8))) __bf16 bf16x8;
typedef __attribute__((ext_vector_type(4))) float  floatx4;

__device__ __forceinline__ unsigned short f2bf(float f) {
    unsigned int u = __float_as_uint(f);
    u = u + 0x7fffu + ((u >> 16) & 1u);     // RNE
    return (unsigned short)(u >> 16);
}

__device__ __forceinline__ void async16(void* lds, const void* g) {
    __builtin_amdgcn_global_load_lds(
        (__attribute__((address_space(1))) void*)g,
        (__attribute__((address_space(3))) void*)lds, 16, 0, 0);
}

// ---------------------------------------------------------------------------
// fused fp32 -> bf16 convert for x and Wenc (one dispatch)
// ---------------------------------------------------------------------------
__global__ __launch_bounds__(256) void ssod_cvt2(const float4* __restrict__ xs, ushort4* __restrict__ xd, int nx4,
                                                 const float4* __restrict__ ws, ushort4* __restrict__ wd, int nw4) {
    const int i = blockIdx.x * 256 + threadIdx.x;
    if (i < nx4) {
        const float4 v = xs[i];
        ushort4 o; o.x = f2bf(v.x); o.y = f2bf(v.y); o.z = f2bf(v.z); o.w = f2bf(v.w);
        xd[i] = o;
    } else {
        const int j = i - nx4;
        if (j < nw4) {
            const float4 v = ws[j];
            ushort4 o; o.x = f2bf(v.x); o.y = f2bf(v.y); o.z = f2bf(v.z); o.w = f2bf(v.w);
            wd[j] = o;
        }
    }
}

// ---------------------------------------------------------------------------
// bf16 MFMA GEMM (m97 structure): 128x128 tile, BK=32, 2x2 waves, 4x4 frags.
// ---------------------------------------------------------------------------
__global__ __launch_bounds__(256) void ssod_gemm_bf16(const unsigned short* __restrict__ A,
                                                      const unsigned short* __restrict__ B,
                                                      unsigned short* __restrict__ C) {
    __shared__ unsigned short As[128 * 32];
    __shared__ unsigned short Bs[128 * 32];

    const int tid  = threadIdx.x;
    const int wave = tid >> 6;
    const int lane = tid & 63;
    const int bn   = blockIdx.x;          // dict tile
    const int bm   = blockIdx.y;          // token tile
    const int wm   = wave >> 1;
    const int wn   = wave & 1;

    const unsigned short* Abase = A + (size_t)bm * 128 * D_MODEL;
    const unsigned short* Bbase = B + (size_t)bn * 128 * D_MODEL;

    floatx4 acc[4][4];
    #pragma unroll
    for (int i = 0; i < 4; ++i)
        #pragma unroll
        for (int j = 0; j < 4; ++j) acc[i][j] = floatx4{0.f, 0.f, 0.f, 0.f};

    const int c0 = wave * 64 + lane;      // 0..255
    const int c1 = c0 + 256;              // 256..511

    const int fr = lane & 15;             // row within 16x16 frag
    const int kg = lane >> 4;             // k-group (8 elems each)

    for (int k0 = 0; k0 < D_MODEL; k0 += 32) {
        async16(&As[c0 * 8], Abase + (size_t)(c0 >> 2) * D_MODEL + k0 + (c0 & 3) * 8);
        async16(&As[c1 * 8], Abase + (size_t)(c1 >> 2) * D_MODEL + k0 + (c1 & 3) * 8);
        async16(&Bs[c0 * 8], Bbase + (size_t)(c0 >> 2) * D_MODEL + k0 + (c0 & 3) * 8);
        async16(&Bs[c1 * 8], Bbase + (size_t)(c1 >> 2) * D_MODEL + k0 + (c1 & 3) * 8);
        __syncthreads();

        bf16x8 af[4], bfr[4];
        #pragma unroll
        for (int f = 0; f < 4; ++f) {
            af[f]  = *(const bf16x8*)&As[(wm * 64 + f * 16 + fr) * 32 + kg * 8];
            bfr[f] = *(const bf16x8*)&Bs[(wn * 64 + f * 16 + fr) * 32 + kg * 8];
        }
        #pragma unroll
        for (int i = 0; i < 4; ++i)
            #pragma unroll
            for (int j = 0; j < 4; ++j)
                acc[i][j] = __builtin_amdgcn_mfma_f32_16x16x32_bf16(af[i], bfr[j], acc[i][j], 0, 0, 0);
        __syncthreads();
    }

    const int col = lane & 15;
    const int rq  = lane >> 4;
    #pragma unroll
    for (int i = 0; i < 4; ++i) {
        const int row = bm * 128 + wm * 64 + i * 16 + rq * 4;
        #pragma unroll
        for (int j = 0; j < 4; ++j) {
            const int ccol = bn * 128 + wn * 64 + j * 16 + col;
            unsigned short* cp = C + (size_t)row * DICT + ccol;
            #pragma unroll
            for (int r = 0; r < 4; ++r)
                cp[(size_t)r * DICT] = f2bf(acc[i][j][r]);
        }
    }
}

// ---------------------------------------------------------------------------
// Fused select + refine + offset. One block (256 thr) per token.
// Phase A: exact bf16 top-16 via threshold filter + 128-key bitonic sort.
// Phase B: fp32 recompute of 16 candidate dots, exact top-8, fused offset.
// ---------------------------------------------------------------------------
__device__ __forceinline__ bool tk_better(float v1, int i1, float v2, int i2) {
    return (v1 > v2) || (v1 == v2 && i1 < i2);
}

__global__ __launch_bounds__(256) void ssod_select_refine(const unsigned short* __restrict__ coeffs,
                                                          const float* __restrict__ x,
                                                          const float* __restrict__ Wenc,
                                                          const float* __restrict__ Wdict,
                                                          float* __restrict__ outp,
                                                          float* __restrict__ tsum,
                                                          int tokBase) {
    const int tl   = blockIdx.x;          // chunk-local token
    const int t    = tokBase + tl;        // global token
    const int tid  = threadIdx.x;
    const int lane = tid & 63;
    const int wave = tid >> 6;

    __shared__ unsigned int smax[256];
    __shared__ unsigned int keys[128];
    __shared__ int cnt;
    __shared__ unsigned int sTau;
    __shared__ float xs[D_MODEL];
    __shared__ int   cidx[NCAND];
    __shared__ float cval[NCAND];
    __shared__ float sval[TOPK];
    __shared__ int   sidx[TOPK];

    // ---- Phase A: top-16 candidate selection from bf16 coeffs ----
    const uint4* row4 = (const uint4*)(coeffs + (size_t)tl * DICT);
    unsigned int d[32];
    #pragma unroll
    for (int i = 0; i < 8; ++i) {
        const uint4 p = row4[i * 256 + tid];
        d[i * 4 + 0] = p.x ^ 0x80008000u;
        d[i * 4 + 1] = p.y ^ 0x80008000u;
        d[i * 4 + 2] = p.z ^ 0x80008000u;
        d[i * 4 + 3] = p.w ^ 0x80008000u;
    }

    unsigned int mx = 0;
    #pragma unroll
    for (int r = 0; r < 32; ++r) {
        const unsigned int hi = d[r] >> 16, lo = d[r] & 0xFFFFu;
        mx = max(mx, max(hi, lo));
    }
    smax[tid] = mx;
    if (tid == 0) cnt = 0;
    // stage x into LDS while phase A proceeds (no dependency)
    ((float4*)xs)[tid] = ((const float4*)(x + (size_t)t * D_MODEL))[tid];
    __syncthreads();

    // wave 0: tau = 16th-largest of 64 group-of-4 maxes
    if (wave == 0) {
        unsigned int g = max(max(smax[4 * lane + 0], smax[4 * lane + 1]),
                             max(smax[4 * lane + 2], smax[4 * lane + 3]));
        for (int k = 2; k <= 64; k <<= 1) {
            for (int j = k >> 1; j >= 1; j >>= 1) {
                const unsigned int p = __shfl_xor(g, j, 64);
                const bool tm = ((lane & j) == 0) ^ ((lane & k) != 0);
                g = tm ? max(g, p) : min(g, p);
            }
        }
        if (lane == 15) sTau = g;
    }
    __syncthreads();
    const unsigned int tau = sTau;

    #pragma unroll
    for (int r = 0; r < 32; ++r) {
        const unsigned int hi = d[r] >> 16, lo = d[r] & 0xFFFFu;
        const int idx = 8 * ((r >> 2) * 256 + tid) + 2 * (r & 3);
        if (lo >= tau) {
            const int p = atomicAdd(&cnt, 1);
            if (p < 128) keys[p] = (lo << 16) | (unsigned)(16383 - idx);
        }
        if (hi >= tau) {
            const int p = atomicAdd(&cnt, 1);
            if (p < 128) keys[p] = (hi << 16) | (unsigned)(16383 - (idx + 1));
        }
    }
    __syncthreads();
    const int m = min(cnt, 128);
    for (int i = m + tid; i < 128; i += 256) keys[i] = 0;
    __syncthreads();

    if (wave == 0) {
        unsigned int v0 = keys[lane], v1 = keys[lane + 64];
        for (int k = 2; k <= 128; k <<= 1) {
            for (int j = k >> 1; j >= 1; j >>= 1) {
                if (j == 64) {
                    const unsigned int a = max(v0, v1), b = min(v0, v1);
                    v0 = a; v1 = b;
                } else {
                    const unsigned int p0 = __shfl_xor(v0, j, 64);
                    const unsigned int p1 = __shfl_xor(v1, j, 64);
                    const bool tm0 = ((lane & j) == 0) ^ ((( lane      ) & k) != 0);
                    const bool tm1 = ((lane & j) == 0) ^ (((lane + 64) & k) != 0);
                    v0 = tm0 ? max(v0, p0) : min(v0, p0);
                    v1 = tm1 ? max(v1, p1) : min(v1, p1);
                }
            }
        }
        if (lane < NCAND) cidx[lane] = 16383 - (int)(v0 & 0xFFFFu);
    }
    __syncthreads();

    // ---- Phase B: fp32 refine of 16 candidates + exact top-8 + offset ----
    const float4* xs4 = (const float4*)xs;
    #pragma unroll
    for (int s = 0; s < 4; ++s) {
        const int c = s * 4 + wave;
        const float4* wr4 = (const float4*)(Wenc + (size_t)cidx[c] * D_MODEL);
        float sum = 0.f;
        #pragma unroll
        for (int q = 0; q < 4; ++q) {
            const float4 xv = xs4[q * 64 + lane];
            const float4 wv = wr4[q * 64 + lane];
            sum += xv.x * wv.x + xv.y * wv.y + xv.z * wv.z + xv.w * wv.w;
        }
        #pragma unroll
        for (int off = 32; off > 0; off >>= 1) sum += __shfl_down(sum, off, 64);
        if (lane == 0) cval[c] = sum;
    }
    __syncthreads();

    if (tid == 0) {
        bool used[NCAND] = {};
        float ssum = 0.f;
        for (int k = 0; k < TOPK; ++k) {
            int best = -1;
            for (int c = 0; c < NCAND; ++c) {
                if (used[c]) continue;
                if (best < 0 || tk_better(cval[c], cidx[c], cval[best], cidx[best])) best = c;
            }
            used[best] = true;
            sval[k] = cval[best]; sidx[k] = cidx[best];
            ssum += fabsf(cval[best]);
        }
        tsum[t] = ssum;
    }
    __syncthreads();

    const int dd = tid * 4;
    float4 a = make_float4(0.f, 0.f, 0.f, 0.f);
    #pragma unroll
    for (int k = 0; k < TOPK; ++k) {
        const float4 r = *(const float4*)(Wdict + (size_t)sidx[k] * D_MODEL + dd);
        const float s = sval[k];
        a.x += s * r.x; a.y += s * r.y; a.z += s * r.z; a.w += s * r.w;
    }
    *(float4*)(outp + (size_t)t * D_MODEL + dd) = a;
}

// ---------------------------------------------------------------------------
// loss = sum(tsum) / (NTOK*DICT)
// ---------------------------------------------------------------------------
__global__ __launch_bounds__(256) void ssod_loss(const float* __restrict__ tsum,
                                                 float* __restrict__ out) {
    float s = 0.f;
    for (int i = threadIdx.x; i < NTOK; i += 256) s += tsum[i];
    #pragma unroll
    for (int off = 32; off > 0; off >>= 1) s += __shfl_down(s, off, 64);
    __shared__ float wsum[4];
    if ((threadIdx.x & 63) == 0) wsum[threadIdx.x >> 6] = s;
    __syncthreads();
    if (threadIdx.x == 0) {
        const float tot = wsum[0] + wsum[1] + wsum[2] + wsum[3];
        out[(size_t)NTOK * D_MODEL] = tot / (float)COEFF_COUNT;
    }
}

// ---------------------------------------------------------------------------
extern "C" void kernel_launch(void* const* d_in, const int* in_sizes, int n_in,
                              void* d_out, int out_size, void* d_ws, size_t ws_size,
                              hipStream_t stream) {
    const float* x     = (const float*)d_in[0];   // [4096,1024]
    const float* Wenc  = (const float*)d_in[1];   // [16384,1024]
    const float* Wdict = (const float*)d_in[2];   // [16384,1024]
    float* out = (float*)d_out;

    char* ws = (char*)d_ws;
    size_t off = 0;
    unsigned short* xbf  = (unsigned short*)(ws + off); off += (size_t)NTOK * D_MODEL * 2;  // 8 MB
    unsigned short* wbf  = (unsigned short*)(ws + off); off += (size_t)DICT * D_MODEL * 2;  // 33.6 MB
    float* tsum = (float*)(ws + off);                   off += (size_t)NTOK * 4;            // 16 KB
    unsigned short* coeffs = (unsigned short*)(ws + off);

    // largest token chunk whose bf16 coeff buffer fits remaining ws
    const size_t remain = (ws_size > off) ? (ws_size - off) : 0;
    int chunk = 512;
    if (remain >= (size_t)4096 * DICT * 2) chunk = 4096;
    else if (remain >= (size_t)2048 * DICT * 2) chunk = 2048;
    else if (remain >= (size_t)1024 * DICT * 2) chunk = 1024;

    const int nx4 = NTOK * D_MODEL / 4;
    const int nw4 = DICT * D_MODEL / 4;
    ssod_cvt2<<<(nx4 + nw4 + 255) / 256, 256, 0, stream>>>(
        (const float4*)x, (ushort4*)xbf, nx4, (const float4*)Wenc, (ushort4*)wbf, nw4);

    for (int tokBase = 0; tokBase < NTOK; tokBase += chunk) {
        dim3 g(DICT / 128, chunk / 128);
        ssod_gemm_bf16<<<g, 256, 0, stream>>>(xbf + (size_t)tokBase * D_MODEL, wbf, coeffs);
        ssod_select_refine<<<chunk, 256, 0, stream>>>(coeffs, x, Wenc, Wdict, out, tsum, tokBase);
    }
    ssod_loss<<<1, 256, 0, stream>>>(tsum, out);
}

// Round 5
// 394.184 us; speedup vs baseline: 1.0648x; 1.0648x over previous
//
#include <hip/hip_runtime.h>
#include <float.h>
#include <stdint.h>

constexpr int D_MODEL = 1024;
constexpr int DICT    = 16384;
constexpr int TOPK    = 8;
constexpr int NCAND   = 16;
constexpr int NTOK    = 4096;      // B*T
constexpr int NTILE   = 128;       // DICT / 128
constexpr long long COEFF_COUNT = (long long)NTOK * DICT;

typedef __attribute__((ext_vector_type(8))) __bf16 bf16x8;
typedef __attribute__((ext_vector_type(4))) float  floatx4;

__device__ __forceinline__ unsigned short f2bf(float f) {
    unsigned int u = __float_as_uint(f);
    u = u + 0x7fffu + ((u >> 16) & 1u);     // RNE
    return (unsigned short)(u >> 16);
}

__device__ __forceinline__ void async16(void* lds, const void* g) {
    __builtin_amdgcn_global_load_lds(
        (__attribute__((address_space(1))) void*)g,
        (__attribute__((address_space(3))) void*)lds, 16, 0, 0);
}

// ---------------------------------------------------------------------------
// fused fp32 -> bf16 convert for x and Wenc (one dispatch)
// ---------------------------------------------------------------------------
__global__ __launch_bounds__(256) void ssod_cvt2(const float4* __restrict__ xs, ushort4* __restrict__ xd, int nx4,
                                                 const float4* __restrict__ ws, ushort4* __restrict__ wd, int nw4) {
    const int i = blockIdx.x * 256 + threadIdx.x;
    if (i < nx4) {
        const float4 v = xs[i];
        ushort4 o; o.x = f2bf(v.x); o.y = f2bf(v.y); o.z = f2bf(v.z); o.w = f2bf(v.w);
        xd[i] = o;
    } else {
        const int j = i - nx4;
        if (j < nw4) {
            const float4 v = ws[j];
            ushort4 o; o.x = f2bf(v.x); o.y = f2bf(v.y); o.z = f2bf(v.z); o.w = f2bf(v.w);
            wd[j] = o;
        }
    }
}

// ---------------------------------------------------------------------------
// bf16 MFMA GEMM (m97 structure) + tile-max epilogue.
// Writes coeffs (bf16) and tmax[token][tile] = max mono16 of the 128-col tile.
// mono16 = bf16bits ^ 0x8000 (upper bound by construction; exact order for
// positives, and the tau region is always positive).
// ---------------------------------------------------------------------------
__global__ __launch_bounds__(256) void ssod_gemm_bf16(const unsigned short* __restrict__ A,
                                                      const unsigned short* __restrict__ B,
                                                      unsigned short* __restrict__ C,
                                                      unsigned short* __restrict__ tmax) {
    __shared__ unsigned short As[128 * 32];
    __shared__ unsigned short Bs[128 * 32];
    __shared__ unsigned int rmax[128];

    const int tid  = threadIdx.x;
    const int wave = tid >> 6;
    const int lane = tid & 63;
    const int bn   = blockIdx.x;          // dict tile
    const int bm   = blockIdx.y;          // token tile
    const int wm   = wave >> 1;
    const int wn   = wave & 1;

    const unsigned short* Abase = A + (size_t)bm * 128 * D_MODEL;
    const unsigned short* Bbase = B + (size_t)bn * 128 * D_MODEL;

    floatx4 acc[4][4];
    #pragma unroll
    for (int i = 0; i < 4; ++i)
        #pragma unroll
        for (int j = 0; j < 4; ++j) acc[i][j] = floatx4{0.f, 0.f, 0.f, 0.f};

    const int c0 = wave * 64 + lane;      // 0..255
    const int c1 = c0 + 256;              // 256..511

    const int fr = lane & 15;             // row within 16x16 frag
    const int kg = lane >> 4;             // k-group (8 elems each)

    for (int k0 = 0; k0 < D_MODEL; k0 += 32) {
        async16(&As[c0 * 8], Abase + (size_t)(c0 >> 2) * D_MODEL + k0 + (c0 & 3) * 8);
        async16(&As[c1 * 8], Abase + (size_t)(c1 >> 2) * D_MODEL + k0 + (c1 & 3) * 8);
        async16(&Bs[c0 * 8], Bbase + (size_t)(c0 >> 2) * D_MODEL + k0 + (c0 & 3) * 8);
        async16(&Bs[c1 * 8], Bbase + (size_t)(c1 >> 2) * D_MODEL + k0 + (c1 & 3) * 8);
        __syncthreads();

        bf16x8 af[4], bfr[4];
        #pragma unroll
        for (int f = 0; f < 4; ++f) {
            af[f]  = *(const bf16x8*)&As[(wm * 64 + f * 16 + fr) * 32 + kg * 8];
            bfr[f] = *(const bf16x8*)&Bs[(wn * 64 + f * 16 + fr) * 32 + kg * 8];
        }
        #pragma unroll
        for (int i = 0; i < 4; ++i)
            #pragma unroll
            for (int j = 0; j < 4; ++j)
                acc[i][j] = __builtin_amdgcn_mfma_f32_16x16x32_bf16(af[i], bfr[j], acc[i][j], 0, 0, 0);
        __syncthreads();
    }

    if (tid < 128) rmax[tid] = 0;

    // C/D layout: col = lane&15, row = (lane>>4)*4 + reg
    const int col = lane & 15;
    const int rq  = lane >> 4;
    unsigned int rowm[4][4];
    #pragma unroll
    for (int i = 0; i < 4; ++i)
        #pragma unroll
        for (int r = 0; r < 4; ++r) rowm[i][r] = 0;

    #pragma unroll
    for (int i = 0; i < 4; ++i) {
        const int row = bm * 128 + wm * 64 + i * 16 + rq * 4;
        #pragma unroll
        for (int j = 0; j < 4; ++j) {
            const int ccol = bn * 128 + wn * 64 + j * 16 + col;
            unsigned short* cp = C + (size_t)row * DICT + ccol;
            #pragma unroll
            for (int r = 0; r < 4; ++r) {
                const unsigned short bf = f2bf(acc[i][j][r]);
                cp[(size_t)r * DICT] = bf;
                rowm[i][r] = max(rowm[i][r], (unsigned int)(bf ^ 0x8000u));
            }
        }
    }
    __syncthreads();   // rmax init visible; stores don't conflict

    // reduce row-part maxes over the 16 col-lanes, then across the 2 wn waves
    #pragma unroll
    for (int i = 0; i < 4; ++i)
        #pragma unroll
        for (int r = 0; r < 4; ++r) {
            unsigned int m = rowm[i][r];
            m = max(m, (unsigned int)__shfl_xor((int)m, 1, 64));
            m = max(m, (unsigned int)__shfl_xor((int)m, 2, 64));
            m = max(m, (unsigned int)__shfl_xor((int)m, 4, 64));
            m = max(m, (unsigned int)__shfl_xor((int)m, 8, 64));
            if ((lane & 15) == 0)
                atomicMax(&rmax[wm * 64 + i * 16 + rq * 4 + r], m);
        }
    __syncthreads();

    if (tid < 128)
        tmax[(size_t)(bm * 128 + tid) * NTILE + bn] = (unsigned short)rmax[tid];
}

// ---------------------------------------------------------------------------
// Fused select + refine + offset. One block (256 thr) per token.
// Phase A: tau = 16th-largest tile-max; read only qualifying tiles (~16-20 of
//          128); collect elems >= tau; bitonic -> exact bf16 top-16.
// Phase B: fp32 recompute of 16 candidate dots, exact top-8, fused offset.
// ---------------------------------------------------------------------------
__device__ __forceinline__ bool tk_better(float v1, int i1, float v2, int i2) {
    return (v1 > v2) || (v1 == v2 && i1 < i2);
}

__global__ __launch_bounds__(256) void ssod_select_refine(const unsigned short* __restrict__ coeffs,
                                                          const unsigned short* __restrict__ tmax,
                                                          const float* __restrict__ x,
                                                          const float* __restrict__ Wenc,
                                                          const float* __restrict__ Wdict,
                                                          float* __restrict__ outp,
                                                          float* __restrict__ tsum,
                                                          int tokBase) {
    const int tl   = blockIdx.x;          // chunk-local token
    const int t    = tokBase + tl;        // global token
    const int tid  = threadIdx.x;
    const int lane = tid & 63;
    const int wave = tid >> 6;

    __shared__ unsigned int keys[128];
    __shared__ int   tlist[64];
    __shared__ int   ncnt, kcnt;
    __shared__ unsigned int sTau;
    __shared__ float xs[D_MODEL];
    __shared__ int   cidx[NCAND];
    __shared__ float cval[NCAND];
    __shared__ float sval[TOPK];
    __shared__ int   sidx[TOPK];

    // stage x into LDS (used in phase B)
    ((float4*)xs)[tid] = ((const float4*)(x + (size_t)t * D_MODEL))[tid];
    if (tid == 0) { ncnt = 0; kcnt = 0; }
    __syncthreads();

    // ---- tau: 16th-largest of the 128 tile maxes (wave 0, 2-reg bitonic) ----
    const unsigned short* tmrow = tmax + (size_t)t * NTILE;
    if (wave == 0) {
        const unsigned int u = ((const unsigned int*)tmrow)[lane];
        unsigned int v0 = u & 0xFFFFu, v1 = u >> 16;
        for (int k = 2; k <= 128; k <<= 1) {
            for (int j = k >> 1; j >= 1; j >>= 1) {
                if (j == 64) {
                    const unsigned int a = max(v0, v1), b = min(v0, v1);
                    v0 = a; v1 = b;
                } else {
                    const unsigned int p0 = __shfl_xor(v0, j, 64);
                    const unsigned int p1 = __shfl_xor(v1, j, 64);
                    const bool tm0 = ((lane & j) == 0) ^ ((( lane      ) & k) != 0);
                    const bool tm1 = ((lane & j) == 0) ^ (((lane + 64) & k) != 0);
                    v0 = tm0 ? max(v0, p0) : min(v0, p0);
                    v1 = tm1 ? max(v1, p1) : min(v1, p1);
                }
            }
        }
        if (lane == 15) sTau = v0;       // descending: lane 15 = 16th largest
    }
    __syncthreads();
    const unsigned int tau = sTau;

    // ---- qualifying tile list (max >= tau): >=16 tiles by construction ----
    if (tid < NTILE) {
        if ((unsigned int)tmrow[tid] >= tau) {
            const int p = atomicAdd(&ncnt, 1);
            if (p < 64) tlist[p] = tid;
        }
    }
    __syncthreads();
    const int nq = min(ncnt, 64);

    // ---- collect elems >= tau from qualifying tiles ----
    const uint4* row4 = (const uint4*)(coeffs + (size_t)tl * DICT);
    for (int j = tid; j < nq * 16; j += 256) {
        const int tile = tlist[j >> 4];
        const int sub  = j & 15;
        const uint4 p = row4[tile * 16 + sub];
        unsigned int w[4] = {p.x ^ 0x80008000u, p.y ^ 0x80008000u,
                             p.z ^ 0x80008000u, p.w ^ 0x80008000u};
        const int base = tile * 128 + sub * 8;
        #pragma unroll
        for (int h = 0; h < 4; ++h) {
            const unsigned int lo = w[h] & 0xFFFFu, hi = w[h] >> 16;
            if (lo >= tau) {
                const int q = atomicAdd(&kcnt, 1);
                if (q < 128) keys[q] = (lo << 16) | (unsigned)(16383 - (base + h * 2));
            }
            if (hi >= tau) {
                const int q = atomicAdd(&kcnt, 1);
                if (q < 128) keys[q] = (hi << 16) | (unsigned)(16383 - (base + h * 2 + 1));
            }
        }
    }
    __syncthreads();
    const int m = min(kcnt, 128);
    for (int i = m + tid; i < 128; i += 256) keys[i] = 0;
    __syncthreads();

    // ---- wave 0: bitonic sort 128 keys desc, emit top-16 indices ----
    if (wave == 0) {
        unsigned int v0 = keys[lane], v1 = keys[lane + 64];
        for (int k = 2; k <= 128; k <<= 1) {
            for (int j = k >> 1; j >= 1; j >>= 1) {
                if (j == 64) {
                    const unsigned int a = max(v0, v1), b = min(v0, v1);
                    v0 = a; v1 = b;
                } else {
                    const unsigned int p0 = __shfl_xor(v0, j, 64);
                    const unsigned int p1 = __shfl_xor(v1, j, 64);
                    const bool tm0 = ((lane & j) == 0) ^ ((( lane      ) & k) != 0);
                    const bool tm1 = ((lane & j) == 0) ^ (((lane + 64) & k) != 0);
                    v0 = tm0 ? max(v0, p0) : min(v0, p0);
                    v1 = tm1 ? max(v1, p1) : min(v1, p1);
                }
            }
        }
        if (lane < NCAND) cidx[lane] = 16383 - (int)(v0 & 0xFFFFu);
    }
    __syncthreads();

    // ---- Phase B: fp32 refine of 16 candidates (4 per wave, loads up front) ----
    const float4* xs4 = (const float4*)xs;
    float4 xv[4];
    #pragma unroll
    for (int q = 0; q < 4; ++q) xv[q] = xs4[q * 64 + lane];

    float4 wv[4][4];
    #pragma unroll
    for (int s = 0; s < 4; ++s) {
        const float4* wr4 = (const float4*)(Wenc + (size_t)cidx[s * 4 + wave] * D_MODEL);
        #pragma unroll
        for (int q = 0; q < 4; ++q) wv[s][q] = wr4[q * 64 + lane];
    }
    #pragma unroll
    for (int s = 0; s < 4; ++s) {
        float sum = 0.f;
        #pragma unroll
        for (int q = 0; q < 4; ++q)
            sum += xv[q].x * wv[s][q].x + xv[q].y * wv[s][q].y +
                   xv[q].z * wv[s][q].z + xv[q].w * wv[s][q].w;
        #pragma unroll
        for (int off = 32; off > 0; off >>= 1) sum += __shfl_down(sum, off, 64);
        if (lane == 0) cval[s * 4 + wave] = sum;
    }
    __syncthreads();

    // ---- parallel rank-based exact top-8 ----
    if (tid < NCAND) {
        const float v = cval[tid];
        const int  ix = cidx[tid];
        int rank = 0;
        #pragma unroll
        for (int j = 0; j < NCAND; ++j)
            rank += (j != tid) && tk_better(cval[j], cidx[j], v, ix);
        if (rank < TOPK) { sval[rank] = v; sidx[rank] = ix; }
    }
    __syncthreads();
    if (tid == 0) {
        float s = 0.f;
        #pragma unroll
        for (int k = 0; k < TOPK; ++k) s += fabsf(sval[k]);
        tsum[t] = s;
    }

    // ---- offset ----
    const int dd = tid * 4;
    float4 a = make_float4(0.f, 0.f, 0.f, 0.f);
    #pragma unroll
    for (int k = 0; k < TOPK; ++k) {
        const float4 r = *(const float4*)(Wdict + (size_t)sidx[k] * D_MODEL + dd);
        const float s = sval[k];
        a.x += s * r.x; a.y += s * r.y; a.z += s * r.z; a.w += s * r.w;
    }
    *(float4*)(outp + (size_t)t * D_MODEL + dd) = a;
}

// ---------------------------------------------------------------------------
// loss = sum(tsum) / (NTOK*DICT)
// ---------------------------------------------------------------------------
__global__ __launch_bounds__(256) void ssod_loss(const float* __restrict__ tsum,
                                                 float* __restrict__ out) {
    float s = 0.f;
    for (int i = threadIdx.x; i < NTOK; i += 256) s += tsum[i];
    #pragma unroll
    for (int off = 32; off > 0; off >>= 1) s += __shfl_down(s, off, 64);
    __shared__ float wsum[4];
    if ((threadIdx.x & 63) == 0) wsum[threadIdx.x >> 6] = s;
    __syncthreads();
    if (threadIdx.x == 0) {
        const float tot = wsum[0] + wsum[1] + wsum[2] + wsum[3];
        out[(size_t)NTOK * D_MODEL] = tot / (float)COEFF_COUNT;
    }
}

// ---------------------------------------------------------------------------
extern "C" void kernel_launch(void* const* d_in, const int* in_sizes, int n_in,
                              void* d_out, int out_size, void* d_ws, size_t ws_size,
                              hipStream_t stream) {
    const float* x     = (const float*)d_in[0];   // [4096,1024]
    const float* Wenc  = (const float*)d_in[1];   // [16384,1024]
    const float* Wdict = (const float*)d_in[2];   // [16384,1024]
    float* out = (float*)d_out;

    char* ws = (char*)d_ws;
    size_t off = 0;
    unsigned short* xbf  = (unsigned short*)(ws + off); off += (size_t)NTOK * D_MODEL * 2;  // 8 MB
    unsigned short* wbf  = (unsigned short*)(ws + off); off += (size_t)DICT * D_MODEL * 2;  // 33.6 MB
    unsigned short* tmax = (unsigned short*)(ws + off); off += (size_t)NTOK * NTILE * 2;    // 1 MB
    float* tsum = (float*)(ws + off);                   off += (size_t)NTOK * 4;            // 16 KB
    unsigned short* coeffs = (unsigned short*)(ws + off);

    // largest token chunk whose bf16 coeff buffer fits remaining ws
    const size_t remain = (ws_size > off) ? (ws_size - off) : 0;
    int chunk = 512;
    if (remain >= (size_t)4096 * DICT * 2) chunk = 4096;
    else if (remain >= (size_t)2048 * DICT * 2) chunk = 2048;
    else if (remain >= (size_t)1024 * DICT * 2) chunk = 1024;

    const int nx4 = NTOK * D_MODEL / 4;
    const int nw4 = DICT * D_MODEL / 4;
    ssod_cvt2<<<(nx4 + nw4 + 255) / 256, 256, 0, stream>>>(
        (const float4*)x, (ushort4*)xbf, nx4, (const float4*)Wenc, (ushort4*)wbf, nw4);

    for (int tokBase = 0; tokBase < NTOK; tokBase += chunk) {
        dim3 g(DICT / 128, chunk / 128);
        ssod_gemm_bf16<<<g, 256, 0, stream>>>(xbf + (size_t)tokBase * D_MODEL, wbf, coeffs,
                                              tmax + (size_t)tokBase * NTILE);
        ssod_select_refine<<<chunk, 256, 0, stream>>>(coeffs, tmax, x, Wenc, Wdict, out, tsum, tokBase);
    }
    ssod_loss<<<1, 256, 0, stream>>>(tsum, out);
}